// Round 13
// baseline (178.288 us; speedup 1.0000x reference)
//
#include <hip/hip_runtime.h>
#include <hip/hip_bf16.h>
#include <math.h>
#include <stdint.h>

#define B_DIM 2
#define S_DIM 2048
#define E_DIM 768
#define H_DIM 8
#define D_DIM 96
#define M_DIM (B_DIM*S_DIM)          // 4096
#define SCALE_F 0.10206207261596575f // 96^-0.5

typedef _Float16 f16x8 __attribute__((ext_vector_type(8)));
typedef float    f32x4  __attribute__((ext_vector_type(4)));
typedef float    f32x16 __attribute__((ext_vector_type(16)));

#define MFMA16H(a,b,c) __builtin_amdgcn_mfma_f32_16x16x32_f16(a,b,c,0,0,0)
#define MFMA32H(a,b,c) __builtin_amdgcn_mfma_f32_32x32x16_f16(a,b,c,0,0,0)

__device__ inline unsigned short f2h(float f) {
    return __builtin_bit_cast(unsigned short, (_Float16)f);
}

// CK-style async global->LDS, 16B per lane.
__device__ inline void gload16(const void* g, void* l) {
    auto gp = reinterpret_cast<const __attribute__((address_space(1))) uint32_t*>(
        reinterpret_cast<uintptr_t>(g));
    auto lp = reinterpret_cast<__attribute__((address_space(3))) uint32_t*>(
        reinterpret_cast<uintptr_t>(l));
    __builtin_amdgcn_global_load_lds(gp, lp, 16, 0, 0);
}

// ---------------------------------------------------------------------------
// Fused preprocessing, ONE launch:
//   blocks [0, 3072):   x [4096,768] fp32 -> fp16
//   blocks [3072, 3504): W{q,k,o} fp32 [k][n] -> W^T fp16 [n][k], 64x64 tiles
// ---------------------------------------------------------------------------
__global__ __launch_bounds__(256) void prep_kernel(
    const float* __restrict__ X,
    const float* __restrict__ W0, const float* __restrict__ W1,
    const float* __restrict__ W2,
    unsigned short* __restrict__ Xf,
    unsigned short* __restrict__ T0, unsigned short* __restrict__ T1,
    unsigned short* __restrict__ T2)
{
    const int tid = threadIdx.x;
    if (blockIdx.x < 3072) {
        int i = (blockIdx.x * 256 + tid) * 4;
        float4 v = *(const float4*)(X + i);
        ushort4 h;
        h.x = f2h(v.x); h.y = f2h(v.y); h.z = f2h(v.z); h.w = f2h(v.w);
        *(ushort4*)(Xf + i) = h;
        return;
    }
    int idx = blockIdx.x - 3072;        // 0..431
    int z = idx / 144, rem = idx % 144;
    const float* W; unsigned short* T;
    if (z == 0)      { W = W0; T = T0; }
    else if (z == 1) { W = W1; T = T1; }
    else             { W = W2; T = T2; }
    int k0 = (rem / 12) << 6, n0 = (rem % 12) << 6;

    __shared__ float tile[64][65];
    const int r = tid >> 4, c4 = (tid & 15) << 2;
    #pragma unroll
    for (int i = 0; i < 4; ++i) {
        float4 v = *(const float4*)(W + (size_t)(k0 + r + i*16)*E_DIM + n0 + c4);
        tile[r + i*16][c4+0] = v.x; tile[r + i*16][c4+1] = v.y;
        tile[r + i*16][c4+2] = v.z; tile[r + i*16][c4+3] = v.w;
    }
    __syncthreads();
    #pragma unroll
    for (int i = 0; i < 4; ++i) {
        int n = r + i*16;
        ushort4 h;
        h.x = f2h(tile[c4+0][n]); h.y = f2h(tile[c4+1][n]);
        h.z = f2h(tile[c4+2][n]); h.w = f2h(tile[c4+3][n]);
        *(ushort4*)(T + (size_t)(n0 + n)*E_DIM + k0 + c4) = h;
    }
}

// ---------------------------------------------------------------------------
// Fused Q/K projection fp16: 128x64 tile, grid (24,32) = 768 blocks = 3/CU.
// BK=64 as two 32-k panels.
// ---------------------------------------------------------------------------
__global__ __launch_bounds__(256) void gemm_qk_kernel(
    const unsigned short* __restrict__ A, const unsigned short* __restrict__ Bt,
    const float* __restrict__ bq, const float* __restrict__ bk,
    unsigned short* __restrict__ Qf, unsigned short* __restrict__ Kf)
{
    __shared__ unsigned short sA[2*128*32];   // [panel][m][k32]
    __shared__ unsigned short sB[2*64*32];    // [panel][n][k32]

    const int tid  = threadIdx.x;
    const int lane = tid & 63;
    const int w    = tid >> 6;
    const int qn   = lane & 15, quad = lane >> 4;
    const int wm   = w & 1, wn = w >> 1;
    const int row0 = blockIdx.y << 7;
    const int col0 = blockIdx.x << 6;   // 64-tiles: Q (<768) / K (>=768) never straddle

    const int ar = tid >> 2;            // 0..63
    const int ak = (tid & 3) << 3;      // 0,8,16,24

    const unsigned short* gA = A  + (size_t)(row0 + ar)*E_DIM + ak;
    const unsigned short* gB = Bt + (size_t)(col0 + ar)*E_DIM + ak;

    f32x4 acc[4][2];
    #pragma unroll
    for (int mt = 0; mt < 4; ++mt)
        #pragma unroll
        for (int nt = 0; nt < 2; ++nt)
            { acc[mt][nt][0]=0.f; acc[mt][nt][1]=0.f; acc[mt][nt][2]=0.f; acc[mt][nt][3]=0.f; }

    for (int k0 = 0; k0 < E_DIM; k0 += 64) {
        __syncthreads();
        gload16(gA + k0,                 sA + tid*8);
        gload16(gA + 64*E_DIM + k0,      sA + 2048 + tid*8);
        gload16(gA + k0 + 32,            sA + 4096 + tid*8);
        gload16(gA + 64*E_DIM + k0 + 32, sA + 6144 + tid*8);
        gload16(gB + k0,                 sB + tid*8);
        gload16(gB + k0 + 32,            sB + 2048 + tid*8);
        __syncthreads();

        #pragma unroll
        for (int kk = 0; kk < 2; ++kk) {
            f16x8 af[4], bf[2];
            #pragma unroll
            for (int mt = 0; mt < 4; ++mt)
                af[mt] = *(const f16x8*)&sA[kk*4096 + (wm*64 + mt*16 + qn)*32 + quad*8];
            #pragma unroll
            for (int nt = 0; nt < 2; ++nt)
                bf[nt] = *(const f16x8*)&sB[kk*2048 + (wn*32 + nt*16 + qn)*32 + quad*8];
            #pragma unroll
            for (int mt = 0; mt < 4; ++mt)
                #pragma unroll
                for (int nt = 0; nt < 2; ++nt)
                    acc[mt][nt] = MFMA16H(af[mt], bf[nt], acc[mt][nt]);
        }
    }

    #pragma unroll
    for (int nt = 0; nt < 2; ++nt) {
        int n = col0 + wn*32 + nt*16 + qn;
        bool isQ = n < E_DIM;
        float bias = isQ ? bq[n] : bk[n - E_DIM];
        unsigned short* op = isQ ? Qf : Kf;
        int nc = isQ ? n : n - E_DIM;
        #pragma unroll
        for (int mt = 0; mt < 4; ++mt)
            #pragma unroll
            for (int r = 0; r < 4; ++r) {
                int m = row0 + wm*64 + mt*16 + quad*4 + r;
                op[(size_t)m*E_DIM + nc] = f2h(acc[mt][nt][r] + bias);
            }
    }
}

// ---------------------------------------------------------------------------
// Flash attention v10: R9's proven kernel (32x32x16, 4 waves, q-tile 128,
// strides 104/72/72, swapped PV, __expf) with KEY-SPLIT x3 (thirds of
// 11/11/10 key-tiles) -> 768 blocks = 3 blocks/CU = 12 waves/CU, so blocks
// at different pipeline phases overlap their MFMA/VALU/LDS usage.
// ---------------------------------------------------------------------------
__global__ __launch_bounds__(256) void attn_mfma_kernel(
    const unsigned short* __restrict__ Qf, const unsigned short* __restrict__ Kf,
    unsigned short* __restrict__ O0, unsigned short* __restrict__ O1,
    unsigned short* __restrict__ O2, float2* __restrict__ ml)
{
    __shared__ unsigned short sKh[64][104];  // [key][d]   16B-multiple rows
    __shared__ unsigned short sKt[96][72];   // [e][key]
    __shared__ unsigned short sPs[128][72];  // [q][key]

    const int tid  = threadIdx.x;
    const int w    = tid >> 6;       // wave 0..3: q rows [w*32, w*32+32)
    const int lane = tid & 63;
    const int col  = lane & 31;      // q for state/S^T-n/PV-n; e for PV-A rows
    const int half = lane >> 5;      // k-half selector
    const int z    = blockIdx.z;
    const int b    = z / 3;
    const int kv   = z % 3;          // key third
    const int h    = blockIdx.y;
    const int q0   = blockIdx.x << 7;
    const int key0 = kv * 704;       // thirds: 704 / 704 / 640 keys
    const int ktiles = (kv < 2) ? 11 : 10;

    // Q B-frags: B[k=d][n=q], lane reads 8 contiguous d at row q=col
    f16x8 qf[6];
    {
        const size_t ro = ((size_t)(b*S_DIM + q0 + w*32 + col))*E_DIM
                          + h*D_DIM + half*8;
        #pragma unroll
        for (int kc = 0; kc < 6; ++kc)
            qf[kc] = *(const f16x8*)(Qf + ro + kc*16);
    }

    f32x16 o[3];
    #pragma unroll
    for (int nt = 0; nt < 3; ++nt)
        #pragma unroll
        for (int r = 0; r < 16; ++r) o[nt][r] = 0.f;
    float m_i = -INFINITY, l_i = 0.f;

    // staging (threads 0-127): rows {2sp, 2sp+1}, d range [dq*24, dq*24+24)
    const bool stager = tid < 128;
    const int st = tid & 127;
    const int sp = st >> 2;          // 0..31
    const int dq = st & 3;           // 0..3

    uint4 r0[3], r1[3];
    if (stager) {
        const size_t g0 = ((size_t)(b*S_DIM + key0 + 2*sp))*E_DIM + h*D_DIM + dq*24;
        #pragma unroll
        for (int i = 0; i < 3; ++i) {
            r0[i] = *(const uint4*)(Kf + g0 + 8*i);
            r1[i] = *(const uint4*)(Kf + g0 + E_DIM + 8*i);
        }
    }

    for (int kt = 0; kt < ktiles; ++kt) {
        __syncthreads();   // previous iteration's K-tile reads complete
        if (stager) {
            #pragma unroll
            for (int i = 0; i < 3; ++i) {
                *(uint4*)&sKh[2*sp  ][dq*24 + 8*i] = r0[i];
                *(uint4*)&sKh[2*sp+1][dq*24 + 8*i] = r1[i];
            }
            const unsigned short* p0 = (const unsigned short*)r0;
            const unsigned short* p1 = (const unsigned short*)r1;
            #pragma unroll
            for (int c = 0; c < 24; ++c) {
                unsigned int pk = (unsigned int)p0[c] | ((unsigned int)p1[c] << 16);
                *(unsigned int*)&sKt[dq*24 + c][2*sp] = pk;
            }
        }
        __syncthreads();   // staging visible

        // prefetch next tile (overlaps with compute below)
        if (stager && kt + 1 < ktiles) {
            const size_t g0 = ((size_t)(b*S_DIM + key0 + (kt+1)*64 + 2*sp))*E_DIM
                              + h*D_DIM + dq*24;
            #pragma unroll
            for (int i = 0; i < 3; ++i) {
                r0[i] = *(const uint4*)(Kf + g0 + 8*i);
                r1[i] = *(const uint4*)(Kf + g0 + E_DIM + 8*i);
            }
        }

        // ---- S^T = K·Q^T (fp16), D[m=key][n=q] ----
        f32x16 s[2];
        #pragma unroll
        for (int mt = 0; mt < 2; ++mt) {
            f32x16 acc;
            #pragma unroll
            for (int r = 0; r < 16; ++r) acc[r] = 0.f;
            #pragma unroll
            for (int kc = 0; kc < 6; ++kc) {
                f16x8 ah = *(const f16x8*)&sKh[mt*32 + col][kc*16 + half*8];
                acc = MFMA32H(ah, qf[kc], acc);
            }
            s[mt] = acc;
        }

        // ---- online softmax, per-lane state (q = col) ----
        float mx = s[0][0];
        #pragma unroll
        for (int mt = 0; mt < 2; ++mt)
            #pragma unroll
            for (int r = 0; r < 16; ++r) mx = fmaxf(mx, s[mt][r]);
        mx = fmaxf(mx, __shfl_xor(mx, 32));

        float m_new = fmaxf(m_i, mx);
        float alpha = __expf(m_i - m_new);
        m_i = m_new;

        float psum = 0.f;
        #pragma unroll
        for (int mt = 0; mt < 2; ++mt)
            #pragma unroll
            for (int g = 0; g < 4; ++g) {
                float e0 = __expf(s[mt][4*g+0] - m_new);
                float e1 = __expf(s[mt][4*g+1] - m_new);
                float e2 = __expf(s[mt][4*g+2] - m_new);
                float e3 = __expf(s[mt][4*g+3] - m_new);
                psum += e0 + e1 + e2 + e3;
                ushort4 pk;
                pk.x = f2h(e0); pk.y = f2h(e1); pk.z = f2h(e2); pk.w = f2h(e3);
                *(ushort4*)&sPs[w*32 + col][mt*32 + 8*g + 4*half] = pk;
            }
        psum += __shfl_xor(psum, 32);
        l_i = l_i * alpha + psum;

        // rescale O: accumulator n-dim = q = col -> lane's own alpha
        #pragma unroll
        for (int nt = 0; nt < 3; ++nt)
            #pragma unroll
            for (int r = 0; r < 16; ++r) o[nt][r] *= alpha;

        // ---- PV swapped: O^T[e][q] += V^T·P^T (A = sKt rows, B = sPs rows) ----
        #pragma unroll
        for (int kc = 0; kc < 4; ++kc) {
            f16x8 pb = *(const f16x8*)&sPs[w*32 + col][kc*16 + half*8];
            #pragma unroll
            for (int nt = 0; nt < 3; ++nt) {
                f16x8 va = *(const f16x8*)&sKt[nt*32 + col][kc*16 + half*8];
                o[nt] = MFMA32H(va, pb, o[nt]);
            }
        }
    }

    // ---- epilogue: unnormalized Ohat (fp16), lane owns row q = col ----
    unsigned short* Ob = (kv == 0 ? O0 : kv == 1 ? O1 : O2)
        + ((size_t)(b*S_DIM + q0 + w*32 + col))*E_DIM + h*D_DIM;
    #pragma unroll
    for (int nt = 0; nt < 3; ++nt)
        #pragma unroll
        for (int rg = 0; rg < 4; ++rg) {
            ushort4 pk;
            pk.x = f2h(o[nt][4*rg+0]); pk.y = f2h(o[nt][4*rg+1]);
            pk.z = f2h(o[nt][4*rg+2]); pk.w = f2h(o[nt][4*rg+3]);
            *(ushort4*)(Ob + nt*32 + 8*rg + 4*half) = pk;
        }
    if (lane < 32) {
        int q = q0 + w*32 + lane;
        ml[((size_t)(kv*B_DIM + b)*H_DIM + h)*S_DIM + q] = make_float2(m_i, l_i);
    }
}

// ---------------------------------------------------------------------------
// 3-way merge scales: s_i = exp(m_i - m) * SCALE / l
// ---------------------------------------------------------------------------
struct Sc3 { float x, y, z; };
__device__ inline Sc3 mkscale3(const float2* __restrict__ ml, int m, int h) {
    int b = m >> 11, q = m & (S_DIM - 1);
    float2 e0 = ml[((size_t)(0*B_DIM + b)*H_DIM + h)*S_DIM + q];
    float2 e1 = ml[((size_t)(1*B_DIM + b)*H_DIM + h)*S_DIM + q];
    float2 e2 = ml[((size_t)(2*B_DIM + b)*H_DIM + h)*S_DIM + q];
    float mm = fmaxf(fmaxf(e0.x, e1.x), e2.x);
    float w0 = __expf(e0.x - mm), w1 = __expf(e1.x - mm), w2 = __expf(e2.x - mm);
    float inv = SCALE_F / (e0.y*w0 + e1.y*w1 + e2.y*w2);
    Sc3 s; s.x = w0*inv; s.y = w1*inv; s.z = w2*inv;
    return s;
}

// ---------------------------------------------------------------------------
// Output projection + fused 3-way partial-combine: 64x64 tile, grid (12,64)
// = 768 blocks = 3/CU. Scales recomputed only at head boundaries (every
// 3rd k-chunk). ctx = O0*s0 + O1*s1 + O2*s2 (packed fp16) in A-staging.
// ---------------------------------------------------------------------------
__global__ __launch_bounds__(256) void gemm_out_kernel(
    const unsigned short* __restrict__ O0, const unsigned short* __restrict__ O1,
    const unsigned short* __restrict__ O2, const float2* __restrict__ ml,
    const unsigned short* __restrict__ Bt, const float* __restrict__ bo,
    float* __restrict__ out)
{
    __shared__ unsigned short sA[64*32];
    __shared__ unsigned short sB[64*32];

    const int tid  = threadIdx.x;
    const int lane = tid & 63;
    const int w    = tid >> 6;
    const int qn   = lane & 15, quad = lane >> 4;
    const int wm   = w & 1, wn = w >> 1;
    const int row0 = blockIdx.y << 6;
    const int col0 = blockIdx.x << 6;

    const int ar = tid >> 2;            // 0..63
    const int ak = (tid & 3) << 3;      // 0,8,16,24

    const size_t r0o = (size_t)(row0 + ar)*E_DIM;
    const unsigned short* gB = Bt + (size_t)(col0 + ar)*E_DIM + ak;

    f32x4 acc[2][2];
    #pragma unroll
    for (int mt = 0; mt < 2; ++mt)
        #pragma unroll
        for (int nt = 0; nt < 2; ++nt)
            { acc[mt][nt][0]=0.f; acc[mt][nt][1]=0.f; acc[mt][nt][2]=0.f; acc[mt][nt][3]=0.f; }

    f16x8 u0 = *(const f16x8*)(O0 + r0o + ak);
    f16x8 v0 = *(const f16x8*)(O1 + r0o + ak);
    f16x8 t0 = *(const f16x8*)(O2 + r0o + ak);
    Sc3 s3 = mkscale3(ml, row0 + ar, 0);
    _Float16 hx = (_Float16)s3.x, hy = (_Float16)s3.y, hz = (_Float16)s3.z;

    for (int k0 = 0; k0 < E_DIM; k0 += 32) {
        __syncthreads();
        {
            f16x8 c0 = u0 * hx + v0 * hy + t0 * hz;
            *(f16x8*)&sA[ar*32 + ak] = c0;
        }
        gload16(gB + k0, sB + tid*8);
        __syncthreads();

        if (k0 + 32 < E_DIM) {
            int kn = k0 + 32;
            u0 = *(const f16x8*)(O0 + r0o + kn + ak);
            v0 = *(const f16x8*)(O1 + r0o + kn + ak);
            t0 = *(const f16x8*)(O2 + r0o + kn + ak);
            if ((kn % D_DIM) == 0) {    // head boundary (every 3rd chunk)
                s3 = mkscale3(ml, row0 + ar, kn / D_DIM);
                hx = (_Float16)s3.x; hy = (_Float16)s3.y; hz = (_Float16)s3.z;
            }
        }

        f16x8 af[2], bf[2];
        #pragma unroll
        for (int mt = 0; mt < 2; ++mt)
            af[mt] = *(const f16x8*)&sA[(wm*32 + mt*16 + qn)*32 + quad*8];
        #pragma unroll
        for (int nt = 0; nt < 2; ++nt)
            bf[nt] = *(const f16x8*)&sB[(wn*32 + nt*16 + qn)*32 + quad*8];
        #pragma unroll
        for (int mt = 0; mt < 2; ++mt)
            #pragma unroll
            for (int nt = 0; nt < 2; ++nt)
                acc[mt][nt] = MFMA16H(af[mt], bf[nt], acc[mt][nt]);
    }

    #pragma unroll
    for (int nt = 0; nt < 2; ++nt) {
        int n = col0 + wn*32 + nt*16 + qn;
        float bias = bo[n];
        #pragma unroll
        for (int mt = 0; mt < 2; ++mt)
            #pragma unroll
            for (int r = 0; r < 4; ++r) {
                int m = row0 + wm*32 + mt*16 + quad*4 + r;
                out[(size_t)m*E_DIM + n] = acc[mt][nt][r] + bias;
            }
    }
}

// ---------------------------------------------------------------------------
extern "C" void kernel_launch(void* const* d_in, const int* in_sizes, int n_in,
                              void* d_out, int out_size, void* d_ws, size_t ws_size,
                              hipStream_t stream)
{
    const float* x  = (const float*)d_in[0];
    const float* Wq = (const float*)d_in[1];
    const float* bq = (const float*)d_in[2];
    const float* Wk = (const float*)d_in[3];
    const float* bk = (const float*)d_in[4];
    const float* Wo = (const float*)d_in[5];
    const float* bo = (const float*)d_in[6];
    float* out = (float*)d_out;

    const size_t NE = (size_t)M_DIM * E_DIM;        // 3.1M elems
    const size_t WE = (size_t)E_DIM * E_DIM;        // 590K elems
    unsigned short* xf    = (unsigned short*)d_ws;  // NE (aliased Oh0 later)
    unsigned short* WqkT  = xf + NE;                // 2*WE  [Wq^T | Wk^T] fp16
    unsigned short* WoT   = WqkT + 2*WE;            // WE
    unsigned short* Qf    = WoT + WE;               // NE
    unsigned short* Kf    = Qf + NE;                // NE
    unsigned short* Oh1   = Kf + NE;                // NE (real ws)
    unsigned short* Oh2   = Oh1 + NE;               // NE (real ws)
    float2*         mlbuf = (float2*)(Oh2 + NE);    // 3*B*H*S float2 = 786 KB
    unsigned short* Oh0   = xf;                     // alias: x dead after gemm_qk

    dim3 blk(256);
    hipLaunchKernelGGL(prep_kernel, dim3(3504), blk, 0, stream,
                       x, Wq, Wk, Wo, xf, WqkT, WqkT + WE, WoT);

    hipLaunchKernelGGL(gemm_qk_kernel, dim3(24,32), blk, 0, stream,
                       xf, WqkT, bq, bk, Qf, Kf);

    hipLaunchKernelGGL(attn_mfma_kernel, dim3(S_DIM/128, H_DIM, B_DIM*3), blk, 0,
                       stream, Qf, Kf, Oh0, Oh1, Oh2, mlbuf);

    hipLaunchKernelGGL(gemm_out_kernel, dim3(12,64), blk, 0, stream,
                       Oh0, Oh1, Oh2, mlbuf, WoT, bo, out);
}

// Round 14
// 163.792 us; speedup vs baseline: 1.0885x; 1.0885x over previous
//
#include <hip/hip_runtime.h>
#include <hip/hip_bf16.h>
#include <math.h>
#include <stdint.h>

#define B_DIM 2
#define S_DIM 2048
#define E_DIM 768
#define H_DIM 8
#define D_DIM 96
#define M_DIM (B_DIM*S_DIM)          // 4096
#define SCALE_F 0.10206207261596575f // 96^-0.5

typedef _Float16 f16x8 __attribute__((ext_vector_type(8)));
typedef float    f32x4  __attribute__((ext_vector_type(4)));
typedef float    f32x16 __attribute__((ext_vector_type(16)));

#define MFMA16H(a,b,c) __builtin_amdgcn_mfma_f32_16x16x32_f16(a,b,c,0,0,0)
#define MFMA32H(a,b,c) __builtin_amdgcn_mfma_f32_32x32x16_f16(a,b,c,0,0,0)

__device__ inline unsigned short f2h(float f) {
    return __builtin_bit_cast(unsigned short, (_Float16)f);
}

// CK-style async global->LDS, 16B per lane.
__device__ inline void gload16(const void* g, void* l) {
    auto gp = reinterpret_cast<const __attribute__((address_space(1))) uint32_t*>(
        reinterpret_cast<uintptr_t>(g));
    auto lp = reinterpret_cast<__attribute__((address_space(3))) uint32_t*>(
        reinterpret_cast<uintptr_t>(l));
    __builtin_amdgcn_global_load_lds(gp, lp, 16, 0, 0);
}

// ---------------------------------------------------------------------------
// Fused preprocessing, ONE launch:
//   blocks [0, 3072):   x [4096,768] fp32 -> fp16
//   blocks [3072, 3504): W{q,k,o} fp32 [k][n] -> W^T fp16 [n][k], 64x64 tiles
// ---------------------------------------------------------------------------
__global__ __launch_bounds__(256) void prep_kernel(
    const float* __restrict__ X,
    const float* __restrict__ W0, const float* __restrict__ W1,
    const float* __restrict__ W2,
    unsigned short* __restrict__ Xf,
    unsigned short* __restrict__ T0, unsigned short* __restrict__ T1,
    unsigned short* __restrict__ T2)
{
    const int tid = threadIdx.x;
    if (blockIdx.x < 3072) {
        int i = (blockIdx.x * 256 + tid) * 4;
        float4 v = *(const float4*)(X + i);
        ushort4 h;
        h.x = f2h(v.x); h.y = f2h(v.y); h.z = f2h(v.z); h.w = f2h(v.w);
        *(ushort4*)(Xf + i) = h;
        return;
    }
    int idx = blockIdx.x - 3072;        // 0..431
    int z = idx / 144, rem = idx % 144;
    const float* W; unsigned short* T;
    if (z == 0)      { W = W0; T = T0; }
    else if (z == 1) { W = W1; T = T1; }
    else             { W = W2; T = T2; }
    int k0 = (rem / 12) << 6, n0 = (rem % 12) << 6;

    __shared__ float tile[64][65];
    const int r = tid >> 4, c4 = (tid & 15) << 2;
    #pragma unroll
    for (int i = 0; i < 4; ++i) {
        float4 v = *(const float4*)(W + (size_t)(k0 + r + i*16)*E_DIM + n0 + c4);
        tile[r + i*16][c4+0] = v.x; tile[r + i*16][c4+1] = v.y;
        tile[r + i*16][c4+2] = v.z; tile[r + i*16][c4+3] = v.w;
    }
    __syncthreads();
    #pragma unroll
    for (int i = 0; i < 4; ++i) {
        int n = r + i*16;
        ushort4 h;
        h.x = f2h(tile[c4+0][n]); h.y = f2h(tile[c4+1][n]);
        h.z = f2h(tile[c4+2][n]); h.w = f2h(tile[c4+3][n]);
        *(ushort4*)(T + (size_t)(n0 + n)*E_DIM + k0 + c4) = h;
    }
}

// ---------------------------------------------------------------------------
// Fused Q/K projection fp16: 128x64 tile, grid (24,32) = 768 blocks = 3/CU.
// BK=64 as two 32-k panels.
// ---------------------------------------------------------------------------
__global__ __launch_bounds__(256) void gemm_qk_kernel(
    const unsigned short* __restrict__ A, const unsigned short* __restrict__ Bt,
    const float* __restrict__ bq, const float* __restrict__ bk,
    unsigned short* __restrict__ Qf, unsigned short* __restrict__ Kf)
{
    __shared__ unsigned short sA[2*128*32];   // [panel][m][k32]
    __shared__ unsigned short sB[2*64*32];    // [panel][n][k32]

    const int tid  = threadIdx.x;
    const int lane = tid & 63;
    const int w    = tid >> 6;
    const int qn   = lane & 15, quad = lane >> 4;
    const int wm   = w & 1, wn = w >> 1;
    const int row0 = blockIdx.y << 7;
    const int col0 = blockIdx.x << 6;   // 64-tiles: Q (<768) / K (>=768) never straddle

    const int ar = tid >> 2;            // 0..63
    const int ak = (tid & 3) << 3;      // 0,8,16,24

    const unsigned short* gA = A  + (size_t)(row0 + ar)*E_DIM + ak;
    const unsigned short* gB = Bt + (size_t)(col0 + ar)*E_DIM + ak;

    f32x4 acc[4][2];
    #pragma unroll
    for (int mt = 0; mt < 4; ++mt)
        #pragma unroll
        for (int nt = 0; nt < 2; ++nt)
            { acc[mt][nt][0]=0.f; acc[mt][nt][1]=0.f; acc[mt][nt][2]=0.f; acc[mt][nt][3]=0.f; }

    for (int k0 = 0; k0 < E_DIM; k0 += 64) {
        __syncthreads();
        gload16(gA + k0,                 sA + tid*8);
        gload16(gA + 64*E_DIM + k0,      sA + 2048 + tid*8);
        gload16(gA + k0 + 32,            sA + 4096 + tid*8);
        gload16(gA + 64*E_DIM + k0 + 32, sA + 6144 + tid*8);
        gload16(gB + k0,                 sB + tid*8);
        gload16(gB + k0 + 32,            sB + 2048 + tid*8);
        __syncthreads();

        #pragma unroll
        for (int kk = 0; kk < 2; ++kk) {
            f16x8 af[4], bf[2];
            #pragma unroll
            for (int mt = 0; mt < 4; ++mt)
                af[mt] = *(const f16x8*)&sA[kk*4096 + (wm*64 + mt*16 + qn)*32 + quad*8];
            #pragma unroll
            for (int nt = 0; nt < 2; ++nt)
                bf[nt] = *(const f16x8*)&sB[kk*2048 + (wn*32 + nt*16 + qn)*32 + quad*8];
            #pragma unroll
            for (int mt = 0; mt < 4; ++mt)
                #pragma unroll
                for (int nt = 0; nt < 2; ++nt)
                    acc[mt][nt] = MFMA16H(af[mt], bf[nt], acc[mt][nt]);
        }
    }

    #pragma unroll
    for (int nt = 0; nt < 2; ++nt) {
        int n = col0 + wn*32 + nt*16 + qn;
        bool isQ = n < E_DIM;
        float bias = isQ ? bq[n] : bk[n - E_DIM];
        unsigned short* op = isQ ? Qf : Kf;
        int nc = isQ ? n : n - E_DIM;
        #pragma unroll
        for (int mt = 0; mt < 4; ++mt)
            #pragma unroll
            for (int r = 0; r < 4; ++r) {
                int m = row0 + wm*64 + mt*16 + quad*4 + r;
                op[(size_t)m*E_DIM + nc] = f2h(acc[mt][nt][r] + bias);
            }
    }
}

// ---------------------------------------------------------------------------
// Flash attention v11: R9-exact schedule (32x32x16, 4 waves, q-tile 128,
// KEY-SPLIT x2 [measured optimum], strides 104/72/72, swapped PV, __expf)
// with DOUBLE-BUFFERED sKh/sKt -> ONE barrier per iteration (16 vs 32).
// Safety: writes to buf[kt&1] at iter kt and reads of the same buffer at
// iter kt-2 are separated by the barrier at iter kt-1. sPs is wave-private.
// ---------------------------------------------------------------------------
__global__ __launch_bounds__(256) void attn_mfma_kernel(
    const unsigned short* __restrict__ Qf, const unsigned short* __restrict__ Kf,
    unsigned short* __restrict__ O0, unsigned short* __restrict__ O1,
    float2* __restrict__ ml)
{
    __shared__ unsigned short sKh[2][64][104];  // [buf][key][d]
    __shared__ unsigned short sKt[2][96][72];   // [buf][e][key]
    __shared__ unsigned short sPs[128][72];     // [q][key]

    const int tid  = threadIdx.x;
    const int w    = tid >> 6;       // wave 0..3: q rows [w*32, w*32+32)
    const int lane = tid & 63;
    const int col  = lane & 31;      // q for state/S^T-n/PV-n; e for PV-A rows
    const int half = lane >> 5;      // k-half selector
    const int b    = blockIdx.z >> 1;
    const int kh   = blockIdx.z & 1; // key half
    const int h    = blockIdx.y;
    const int q0   = blockIdx.x << 7;
    const int key0 = kh << 10;       // 0 or 1024

    // Q B-frags: B[k=d][n=q], lane reads 8 contiguous d at row q=col
    f16x8 qf[6];
    {
        const size_t ro = ((size_t)(b*S_DIM + q0 + w*32 + col))*E_DIM
                          + h*D_DIM + half*8;
        #pragma unroll
        for (int kc = 0; kc < 6; ++kc)
            qf[kc] = *(const f16x8*)(Qf + ro + kc*16);
    }

    f32x16 o[3];
    #pragma unroll
    for (int nt = 0; nt < 3; ++nt)
        #pragma unroll
        for (int r = 0; r < 16; ++r) o[nt][r] = 0.f;
    float m_i = -INFINITY, l_i = 0.f;

    // staging (threads 0-127): rows {2sp, 2sp+1}, d range [dq*24, dq*24+24)
    const bool stager = tid < 128;
    const int st = tid & 127;
    const int sp = st >> 2;          // 0..31
    const int dq = st & 3;           // 0..3

    uint4 r0[3], r1[3];
    if (stager) {
        const size_t g0 = ((size_t)(b*S_DIM + key0 + 2*sp))*E_DIM + h*D_DIM + dq*24;
        #pragma unroll
        for (int i = 0; i < 3; ++i) {
            r0[i] = *(const uint4*)(Kf + g0 + 8*i);
            r1[i] = *(const uint4*)(Kf + g0 + E_DIM + 8*i);
        }
    }

    for (int kt = 0; kt < 16; ++kt) {
        const int p = kt & 1;
        if (stager) {
            #pragma unroll
            for (int i = 0; i < 3; ++i) {
                *(uint4*)&sKh[p][2*sp  ][dq*24 + 8*i] = r0[i];
                *(uint4*)&sKh[p][2*sp+1][dq*24 + 8*i] = r1[i];
            }
            const unsigned short* p0 = (const unsigned short*)r0;
            const unsigned short* p1 = (const unsigned short*)r1;
            #pragma unroll
            for (int c = 0; c < 24; ++c) {
                unsigned int pk = (unsigned int)p0[c] | ((unsigned int)p1[c] << 16);
                *(unsigned int*)&sKt[p][dq*24 + c][2*sp] = pk;
            }
        }
        __syncthreads();   // buf[p] visible; also fences buf[p] reads of kt-2

        // prefetch next tile (overlaps with compute below)
        if (stager && kt + 1 < 16) {
            const size_t g0 = ((size_t)(b*S_DIM + key0 + (kt+1)*64 + 2*sp))*E_DIM
                              + h*D_DIM + dq*24;
            #pragma unroll
            for (int i = 0; i < 3; ++i) {
                r0[i] = *(const uint4*)(Kf + g0 + 8*i);
                r1[i] = *(const uint4*)(Kf + g0 + E_DIM + 8*i);
            }
        }

        // ---- S^T = K·Q^T (fp16), D[m=key][n=q] ----
        f32x16 s[2];
        #pragma unroll
        for (int mt = 0; mt < 2; ++mt) {
            f32x16 acc;
            #pragma unroll
            for (int r = 0; r < 16; ++r) acc[r] = 0.f;
            #pragma unroll
            for (int kc = 0; kc < 6; ++kc) {
                f16x8 ah = *(const f16x8*)&sKh[p][mt*32 + col][kc*16 + half*8];
                acc = MFMA32H(ah, qf[kc], acc);
            }
            s[mt] = acc;
        }

        // ---- online softmax, per-lane state (q = col) ----
        float mx = s[0][0];
        #pragma unroll
        for (int mt = 0; mt < 2; ++mt)
            #pragma unroll
            for (int r = 0; r < 16; ++r) mx = fmaxf(mx, s[mt][r]);
        mx = fmaxf(mx, __shfl_xor(mx, 32));

        float m_new = fmaxf(m_i, mx);
        float alpha = __expf(m_i - m_new);
        m_i = m_new;

        float psum = 0.f;
        #pragma unroll
        for (int mt = 0; mt < 2; ++mt)
            #pragma unroll
            for (int g = 0; g < 4; ++g) {
                float e0 = __expf(s[mt][4*g+0] - m_new);
                float e1 = __expf(s[mt][4*g+1] - m_new);
                float e2 = __expf(s[mt][4*g+2] - m_new);
                float e3 = __expf(s[mt][4*g+3] - m_new);
                psum += e0 + e1 + e2 + e3;
                ushort4 pk;
                pk.x = f2h(e0); pk.y = f2h(e1); pk.z = f2h(e2); pk.w = f2h(e3);
                *(ushort4*)&sPs[w*32 + col][mt*32 + 8*g + 4*half] = pk;
            }
        psum += __shfl_xor(psum, 32);
        l_i = l_i * alpha + psum;

        // rescale O: accumulator n-dim = q = col -> lane's own alpha
        #pragma unroll
        for (int nt = 0; nt < 3; ++nt)
            #pragma unroll
            for (int r = 0; r < 16; ++r) o[nt][r] *= alpha;

        // ---- PV swapped: O^T[e][q] += V^T·P^T (A = sKt rows, B = sPs rows) ----
        #pragma unroll
        for (int kc = 0; kc < 4; ++kc) {
            f16x8 pb = *(const f16x8*)&sPs[w*32 + col][kc*16 + half*8];
            #pragma unroll
            for (int nt = 0; nt < 3; ++nt) {
                f16x8 va = *(const f16x8*)&sKt[p][nt*32 + col][kc*16 + half*8];
                o[nt] = MFMA32H(va, pb, o[nt]);
            }
        }
    }

    // ---- epilogue: unnormalized Ohat (fp16), lane owns row q = col ----
    unsigned short* Ob = (kh ? O1 : O0)
        + ((size_t)(b*S_DIM + q0 + w*32 + col))*E_DIM + h*D_DIM;
    #pragma unroll
    for (int nt = 0; nt < 3; ++nt)
        #pragma unroll
        for (int rg = 0; rg < 4; ++rg) {
            ushort4 pk;
            pk.x = f2h(o[nt][4*rg+0]); pk.y = f2h(o[nt][4*rg+1]);
            pk.z = f2h(o[nt][4*rg+2]); pk.w = f2h(o[nt][4*rg+3]);
            *(ushort4*)(Ob + nt*32 + 8*rg + 4*half) = pk;
        }
    if (lane < 32) {
        int q = q0 + w*32 + lane;
        ml[((size_t)(kh*B_DIM + b)*H_DIM + h)*S_DIM + q] = make_float2(m_i, l_i);
    }
}

// ---------------------------------------------------------------------------
// Merge scales from (m,l), computed inline: s_i = exp(m_i - m) * SCALE / l
// ---------------------------------------------------------------------------
__device__ inline float2 mkscale(const float2* __restrict__ ml, int m, int h) {
    int b = m >> 11, q = m & (S_DIM - 1);
    float2 e0 = ml[((size_t)b*H_DIM + h)*S_DIM + q];
    float2 e1 = ml[((size_t)(B_DIM + b)*H_DIM + h)*S_DIM + q];
    float mm = fmaxf(e0.x, e1.x);
    float w0 = __expf(e0.x - mm), w1 = __expf(e1.x - mm);
    float inv = SCALE_F / (e0.y*w0 + e1.y*w1);
    return make_float2(w0*inv, w1*inv);
}

// ---------------------------------------------------------------------------
// Output projection + fused partial-combine: 64x64 tile, grid (12,64) = 768
// blocks = 3/CU. ctx = O0*s0 + O1*s1 (packed fp16) in A-staging; scales
// recomputed only at head boundaries. out = ctx·Wo^T + bo (fp32).
// ---------------------------------------------------------------------------
__global__ __launch_bounds__(256) void gemm_out_kernel(
    const unsigned short* __restrict__ O0, const unsigned short* __restrict__ O1,
    const float2* __restrict__ ml, const unsigned short* __restrict__ Bt,
    const float* __restrict__ bo, float* __restrict__ out)
{
    __shared__ unsigned short sA[64*32];
    __shared__ unsigned short sB[64*32];

    const int tid  = threadIdx.x;
    const int lane = tid & 63;
    const int w    = tid >> 6;
    const int qn   = lane & 15, quad = lane >> 4;
    const int wm   = w & 1, wn = w >> 1;
    const int row0 = blockIdx.y << 6;
    const int col0 = blockIdx.x << 6;

    const int ar = tid >> 2;            // 0..63
    const int ak = (tid & 3) << 3;      // 0,8,16,24

    const size_t r0o = (size_t)(row0 + ar)*E_DIM;
    const unsigned short* gB = Bt + (size_t)(col0 + ar)*E_DIM + ak;

    f32x4 acc[2][2];
    #pragma unroll
    for (int mt = 0; mt < 2; ++mt)
        #pragma unroll
        for (int nt = 0; nt < 2; ++nt)
            { acc[mt][nt][0]=0.f; acc[mt][nt][1]=0.f; acc[mt][nt][2]=0.f; acc[mt][nt][3]=0.f; }

    f16x8 u0 = *(const f16x8*)(O0 + r0o + ak);
    f16x8 v0 = *(const f16x8*)(O1 + r0o + ak);
    float2 s0 = mkscale(ml, row0 + ar, 0);
    _Float16 hx = (_Float16)s0.x, hy = (_Float16)s0.y;

    for (int k0 = 0; k0 < E_DIM; k0 += 32) {
        __syncthreads();
        {
            f16x8 c0 = u0 * hx + v0 * hy;
            *(f16x8*)&sA[ar*32 + ak] = c0;
        }
        gload16(gB + k0, sB + tid*8);
        __syncthreads();

        if (k0 + 32 < E_DIM) {
            int kn = k0 + 32;
            u0 = *(const f16x8*)(O0 + r0o + kn + ak);
            v0 = *(const f16x8*)(O1 + r0o + kn + ak);
            if ((kn % D_DIM) == 0) {    // head boundary (every 3rd chunk)
                s0 = mkscale(ml, row0 + ar, kn / D_DIM);
                hx = (_Float16)s0.x; hy = (_Float16)s0.y;
            }
        }

        f16x8 af[2], bf[2];
        #pragma unroll
        for (int mt = 0; mt < 2; ++mt)
            af[mt] = *(const f16x8*)&sA[(wm*32 + mt*16 + qn)*32 + quad*8];
        #pragma unroll
        for (int nt = 0; nt < 2; ++nt)
            bf[nt] = *(const f16x8*)&sB[(wn*32 + nt*16 + qn)*32 + quad*8];
        #pragma unroll
        for (int mt = 0; mt < 2; ++mt)
            #pragma unroll
            for (int nt = 0; nt < 2; ++nt)
                acc[mt][nt] = MFMA16H(af[mt], bf[nt], acc[mt][nt]);
    }

    #pragma unroll
    for (int nt = 0; nt < 2; ++nt) {
        int n = col0 + wn*32 + nt*16 + qn;
        float bias = bo[n];
        #pragma unroll
        for (int mt = 0; mt < 2; ++mt)
            #pragma unroll
            for (int r = 0; r < 4; ++r) {
                int m = row0 + wm*32 + mt*16 + quad*4 + r;
                out[(size_t)m*E_DIM + n] = acc[mt][nt][r] + bias;
            }
    }
}

// ---------------------------------------------------------------------------
extern "C" void kernel_launch(void* const* d_in, const int* in_sizes, int n_in,
                              void* d_out, int out_size, void* d_ws, size_t ws_size,
                              hipStream_t stream)
{
    const float* x  = (const float*)d_in[0];
    const float* Wq = (const float*)d_in[1];
    const float* bq = (const float*)d_in[2];
    const float* Wk = (const float*)d_in[3];
    const float* bk = (const float*)d_in[4];
    const float* Wo = (const float*)d_in[5];
    const float* bo = (const float*)d_in[6];
    float* out = (float*)d_out;

    const size_t NE = (size_t)M_DIM * E_DIM;        // 3.1M elems
    const size_t WE = (size_t)E_DIM * E_DIM;        // 590K elems
    unsigned short* xf    = (unsigned short*)d_ws;  // NE (aliased Oh0 later)
    unsigned short* WqkT  = xf + NE;                // 2*WE  [Wq^T | Wk^T] fp16
    unsigned short* WoT   = WqkT + 2*WE;            // WE
    unsigned short* Qf    = WoT + WE;               // NE
    unsigned short* Kf    = Qf + NE;                // NE
    unsigned short* Oh1   = Kf + NE;                // NE (real ws)
    float2*         mlbuf = (float2*)(Oh1 + NE);    // 2*B*H*S float2 = 512 KB
    unsigned short* Oh0   = xf;                     // alias: x dead after gemm_qk

    dim3 blk(256);
    hipLaunchKernelGGL(prep_kernel, dim3(3504), blk, 0, stream,
                       x, Wq, Wk, Wo, xf, WqkT, WqkT + WE, WoT);

    hipLaunchKernelGGL(gemm_qk_kernel, dim3(24,32), blk, 0, stream,
                       xf, WqkT, bq, bk, Qf, Kf);

    hipLaunchKernelGGL(attn_mfma_kernel, dim3(S_DIM/128, H_DIM, B_DIM*2), blk, 0,
                       stream, Qf, Kf, Oh0, Oh1, mlbuf);

    hipLaunchKernelGGL(gemm_out_kernel, dim3(12,64), blk, 0, stream,
                       Oh0, Oh1, mlbuf, WoT, bo, out);
}